// Round 2
// baseline (528.858 us; speedup 1.0000x reference)
//
#include <hip/hip_runtime.h>

#define LOG2E 1.4426950408889634f
#define LN2   0.6931471805599453f
#define NEGF  -1.0e30f
#define EMS   132   // emission row stride (floats): [0..L-1]=labels, [L]=blank, pad

__device__ __forceinline__ float x2(float x) { return __builtin_amdgcn_exp2f(x); }
__device__ __forceinline__ float lg2(float x) { return __builtin_amdgcn_logf(x); }

// lse2 in log2 domain via |diff|: 2 transcendentals. Sentinel-safe:
// both NEG -> NEG+1; one NEG -> other exactly.
__device__ __forceinline__ float lse2(float x, float y) {
    float m = fmaxf(x, y);
    float d = -fabsf(x - y);
    return m + lg2(1.0f + x2(d));
}

// lse3 in log2 domain: 4 transcendentals. All-NEG -> ~NEG.
__device__ __forceinline__ float lse3(float x, float y, float z) {
    float m = fmaxf(fmaxf(x, y), z);
    float s = x2(x - m) + x2(y - m) + x2(z - m);
    return m + lg2(s);
}

// Phase 1 (fused): per-(b,t) log-softmax normalizer + gather the 129 token
// log-probs (base-2) into em[row][0..L]. One wave per row, 4 waves/block,
// no LDS, no barriers. V <= 1024, V%4==0.
__global__ __launch_bounds__(256) void emit_kernel(const float* __restrict__ pred,
                                                   const int* __restrict__ target,
                                                   float* __restrict__ em,
                                                   int T, int V, int L) {
    int wave = threadIdx.x >> 6;
    int lane = threadIdx.x & 63;
    int row = blockIdx.x * 4 + wave;            // row = b*T + t
    const float* rowp = pred + (size_t)row * V;
    int nq = V >> 2;                            // 250 float4s
    float4 v[4];
    float lm = -3.0e38f;
    #pragma unroll
    for (int k = 0; k < 4; ++k) {
        int q = lane + 64 * k;
        if (q < nq) v[k] = ((const float4*)rowp)[q];
        else v[k] = make_float4(-3.0e38f, -3.0e38f, -3.0e38f, -3.0e38f);
        lm = fmaxf(lm, fmaxf(fmaxf(v[k].x, v[k].y), fmaxf(v[k].z, v[k].w)));
    }
    #pragma unroll
    for (int off = 32; off > 0; off >>= 1) lm = fmaxf(lm, __shfl_xor(lm, off));
    float mm = lm * LOG2E;                      // row max in log2 units
    float ls = 0.f;
    #pragma unroll
    for (int k = 0; k < 4; ++k) {
        int q = lane + 64 * k;
        if (q < nq) {
            ls += x2(fmaf(v[k].x, LOG2E, -mm)) + x2(fmaf(v[k].y, LOG2E, -mm))
                + x2(fmaf(v[k].z, LOG2E, -mm)) + x2(fmaf(v[k].w, LOG2E, -mm));
        }
    }
    #pragma unroll
    for (int off = 32; off > 0; off >>= 1) ls += __shfl_xor(ls, off);
    float n2 = mm + lg2(ls);                    // log2(sum exp) normalizer

    int b = row / T;
    const int* tg = target + b * L;
    float* emrow = em + (size_t)row * EMS;
    for (int j = lane; j <= L; j += 64) {       // j==L is the blank (token 0)
        int tok = (j < L) ? tg[j] : 0;
        emrow[j] = fmaf(rowp[tok], LOG2E, -n2); // L1-hot gather (row just read)
    }
}

// Phase 2: barrier-free single-wave W-CTC DP. Lane i owns extended states
// s = 4i+2 .. 4i+5 (label 2i, blank, label 2i+1, blank) in registers; the
// star state s=0 is identically 0 (self-loop, emission 0); state s=1 is a
// side register on lane 0. Cross-lane alpha[s-1]/alpha[s-2] via shfl_up.
// States beyond 2*tl+1 evolve freely — transitions only flow rightward, so
// they never contaminate the readout states ll=2tl, lb=2tl+1.
// total = lse over t=0..T-1 of (alpha_t[ll], alpha_t[lb]) — this equals
// lse(endstar_T, alpha_{T-1}[ll], alpha_{T-1}[lb]) in the reference.
__global__ __launch_bounds__(64) void dp_kernel(const float* __restrict__ em,
                                                const int* __restrict__ target,
                                                const int* __restrict__ tlen,
                                                float* __restrict__ nll,
                                                int T, int L) {
    int b = blockIdx.x;
    int lane = threadIdx.x;
    const float* embase = em + (size_t)b * T * EMS;
    const int* tg = target + b * L;

    int t0 = tg[2 * lane];          // label 2i token
    int t1 = tg[2 * lane + 1];      // label 2i+1 token
    int tprev = __shfl_up(t1, 1);   // label 2i-1 token (garbage on lane 0)
    bool skipA = (lane == 0) || (t0 != tprev);   // s=2 skip always allowed
    bool skipB = (t1 != t0);

    int tl = tlen[b];
    int ll = 2 * tl;
    int lane_e = (ll - 2) >> 2;
    bool slot0 = ((ll - 2) & 3) == 0;   // ll,lb sit in regs (a0,a1) vs (a2,a3)

    // t = 0 init (alpha0: s=0 -> 0, s=1 -> blank em, s=2 -> label0 em)
    float2 e0 = *(const float2*)(embase + 2 * lane);
    float eB0 = embase[L];
    float a0 = (lane == 0) ? e0.x : NEGF;   // s=4i+2
    float a1 = NEGF;                        // s=4i+3
    float a2 = NEGF;                        // s=4i+4
    float a3 = NEGF;                        // s=4i+5
    float s1 = (lane == 0) ? eB0 : NEGF;    // side state s=1

    // running lse of (alpha_t[ll], alpha_t[lb]) as (max, scaled-sum)
    float m_es = NEGF, s_es = 0.f;
    {
        float av1 = slot0 ? a0 : a2;
        float av2 = slot0 ? a1 : a3;
        float mn = fmaxf(m_es, fmaxf(av1, av2));
        s_es = s_es * x2(m_es - mn) + x2(av1 - mn) + x2(av2 - mn);
        m_es = mn;
    }

    // depth-2 emission prefetch pipeline (no barriers -> latency overlapped)
    float2 eL[2]; float eB[2];
    {
        const float* p1 = embase + (size_t)1 * EMS;
        eL[0] = *(const float2*)(p1 + 2 * lane); eB[0] = p1[L];
        const float* p2 = embase + (size_t)2 * EMS;
        eL[1] = *(const float2*)(p2 + 2 * lane); eB[1] = p2[L];
    }

    #pragma unroll 2
    for (int t = 1; t < T; ++t) {
        int ib = (t - 1) & 1;
        float ex0 = eL[ib].x, ex1 = eL[ib].y, eb = eB[ib];
        int tpre = t + 2; if (tpre > T - 1) tpre = T - 1;
        const float* pp = embase + (size_t)tpre * EMS;
        eL[ib] = *(const float2*)(pp + 2 * lane);
        eB[ib] = pp[L];

        float u2 = __shfl_up(a2, 1);    // alpha_{t-1}[4i]   (s-2 for state 4i+2)
        float u3 = __shfl_up(a3, 1);    // alpha_{t-1}[4i+1] (s-1 for state 4i+2)
        if (lane == 0) { u2 = 0.0f; u3 = s1; }   // star=0, side blank

        float s1n = eb  + lse2(s1, 0.0f);                       // s=1
        float n0  = ex0 + lse3(a0, u3, skipA ? u2 : NEGF);      // s=4i+2
        float n1  = eb  + lse2(a1, a0);                         // s=4i+3
        float n2v = ex1 + lse3(a2, a1, skipB ? a0 : NEGF);      // s=4i+4
        float n3  = eb  + lse2(a3, a2);                         // s=4i+5
        a0 = n0; a1 = n1; a2 = n2v; a3 = n3; s1 = s1n;

        float av1 = slot0 ? a0 : a2;
        float av2 = slot0 ? a1 : a3;
        float mn = fmaxf(m_es, fmaxf(av1, av2));
        s_es = s_es * x2(m_es - mn) + x2(av1 - mn) + x2(av2 - mn);
        m_es = mn;
    }

    float mt = __shfl(m_es, lane_e);
    float st = __shfl(s_es, lane_e);
    if (lane == 0) {
        float total = mt + lg2(st);
        nll[b] = -(total * LN2);    // back to nats
    }
}

// Phase 3: out = mean_b( nll[b] / tlen[b] )
__global__ __launch_bounds__(64) void fin_kernel(const float* __restrict__ nll,
                                                 const int* __restrict__ tlen,
                                                 float* __restrict__ out, int B) {
    int tid = threadIdx.x;
    float v = (tid < B) ? nll[tid] / (float)tlen[tid] : 0.f;
    #pragma unroll
    for (int off = 32; off > 0; off >>= 1) v += __shfl_xor(v, off);
    if (tid == 0) out[0] = v / (float)B;
}

extern "C" void kernel_launch(void* const* d_in, const int* in_sizes, int n_in,
                              void* d_out, int out_size, void* d_ws, size_t ws_size,
                              hipStream_t stream) {
    const float* pred   = (const float*)d_in[0];
    const int*   target = (const int*)d_in[1];
    const int*   tlen   = (const int*)d_in[2];
    int B = in_sizes[2];
    int L = in_sizes[1] / B;            // 128
    int V = 1000;                       // fixed by the problem
    int T = in_sizes[0] / (B * V);      // 1024

    float* ws  = (float*)d_ws;
    float* nll = ws;                    // 64 floats
    float* em  = ws + 64;               // B*T*EMS floats (~17.3 MB), fully
                                        // rewritten by emit_kernel each launch

    emit_kernel<<<(B * T) / 4, 256, 0, stream>>>(pred, target, em, T, V, L);
    dp_kernel<<<B, 64, 0, stream>>>(em, target, tlen, nll, T, L);
    fin_kernel<<<1, 64, 0, stream>>>(nll, tlen, (float*)d_out, B);
}

// Round 3
// 515.288 us; speedup vs baseline: 1.0263x; 1.0263x over previous
//
#include <hip/hip_runtime.h>

#define LOG2E 1.4426950408889634f
#define LN2   0.6931471805599453f
#define NEGF  -1.0e30f
#define PF    8    // dp emission prefetch depth (iterations of latency cover)

__device__ __forceinline__ float x2(float x)  { return __builtin_amdgcn_exp2f(x); }
__device__ __forceinline__ float lg2(float x) { return __builtin_amdgcn_logf(x); }

// lse2 in log2 domain: 2 transcendentals (the -|x-y| folds into exp2's input
// modifiers). Sentinel-safe: both NEG -> NEG+1; one NEG -> other exactly.
__device__ __forceinline__ float lse2(float x, float y) {
    float m = fmaxf(x, y);
    float d = -fabsf(x - y);
    return m + lg2(1.0f + x2(d));
}

// Phase 1: per-(b,t) log-softmax normalizer + gather token log2-probs.
// Labels -> em[row*128 + j] (stride 128 floats = one coalesced 512B float2
// wave-load per DP step); blank -> emb[row] (compact 4KB/sample).
// One wave per row, 4 waves/block, no LDS, no barriers.
__global__ __launch_bounds__(256) void emit_kernel(const float* __restrict__ pred,
                                                   const int* __restrict__ target,
                                                   float* __restrict__ em,
                                                   float* __restrict__ emb,
                                                   int T, int V, int L) {
    int wave = threadIdx.x >> 6;
    int lane = threadIdx.x & 63;
    int row = blockIdx.x * 4 + wave;            // row = b*T + t
    const float* rowp = pred + (size_t)row * V;
    int nq = V >> 2;                            // 250 float4s
    float4 v[4];
    float lm = -3.0e38f;
    #pragma unroll
    for (int k = 0; k < 4; ++k) {
        int q = lane + 64 * k;
        if (q < nq) v[k] = ((const float4*)rowp)[q];
        else v[k] = make_float4(-3.0e38f, -3.0e38f, -3.0e38f, -3.0e38f);
        lm = fmaxf(lm, fmaxf(fmaxf(v[k].x, v[k].y), fmaxf(v[k].z, v[k].w)));
    }
    #pragma unroll
    for (int off = 32; off > 0; off >>= 1) lm = fmaxf(lm, __shfl_xor(lm, off));
    float mm = lm * LOG2E;                      // row max in log2 units
    float ls = 0.f;
    #pragma unroll
    for (int k = 0; k < 4; ++k) {
        int q = lane + 64 * k;
        if (q < nq) {
            ls += x2(fmaf(v[k].x, LOG2E, -mm)) + x2(fmaf(v[k].y, LOG2E, -mm))
                + x2(fmaf(v[k].z, LOG2E, -mm)) + x2(fmaf(v[k].w, LOG2E, -mm));
        }
    }
    #pragma unroll
    for (int off = 32; off > 0; off >>= 1) ls += __shfl_xor(ls, off);
    float n2 = mm + lg2(ls);                    // log2 normalizer

    int b = row / T;
    const int* tg = target + b * L;
    float* emrow = em + (size_t)row * 128;
    for (int j = lane; j < L; j += 64) {
        int tok = tg[j];
        emrow[j] = fmaf(rowp[tok], LOG2E, -n2); // L1-hot gather (row just read)
    }
    if (lane == 0) emb[row] = fmaf(v[0].x, LOG2E, -n2);  // blank = token 0
}

// Phase 2: barrier-free single-wave W-CTC DP, log2 domain. Lane i owns
// states s=4i+2..4i+5 in registers; star (s=0, identically 0) and s=1 are
// lane-0 side state. 12 transcendentals/step via lse-fusion:
//   q = lse2(a1,a0): n1 core, n2 skip input, end-star slot0 contribution
//   r = lse2(a3,a2): n3 core, shfl(r) = n0 combined (s-1,s-2), es slot1
// End-star/total accumulates PRE-update alpha_{t-1}[ll],[lb] in-loop
// (t=1..T-1 covers alpha_0..alpha_{T-2}) + one post-loop alpha_{T-1} step.
// Emissions prefetched PF iterations ahead (no barriers -> fully overlapped).
__global__ __launch_bounds__(64) void dp_kernel(const float* __restrict__ em,
                                                const float* __restrict__ emb,
                                                const int* __restrict__ target,
                                                const int* __restrict__ tlen,
                                                float* __restrict__ nll,
                                                int T, int L) {
    int b = blockIdx.x;
    int lane = threadIdx.x;
    const float* eLb = em + (size_t)b * T * 128;
    const float* eBb = emb + (size_t)b * T;
    const int* tg = target + b * L;

    int t0 = tg[2 * lane];
    int t1 = tg[2 * lane + 1];
    int tprev = __shfl_up(t1, 1);                // garbage on lane 0 (unused)
    bool skipA = (lane == 0) || (t0 != tprev);
    bool skipB = (t1 != t0);

    int tl = tlen[b];
    int ll = 2 * tl;
    int lane_e = (ll - 2) >> 2;
    bool slot0 = ((ll - 2) & 3) == 0;            // ll,lb in (a0,a1) vs (a2,a3)

    // t=0 init: s=0 -> 0 (constant star), s=1 -> blank em, s=2 -> label0 em
    float2 e0 = *(const float2*)(eLb + 2 * lane);
    float a0 = (lane == 0) ? e0.x : NEGF;
    float a1 = NEGF, a2 = NEGF, a3 = NEGF;
    float s1 = (lane == 0) ? eBb[0] : NEGF;

    float m_es = NEGF, s_es = 0.f;               // streaming lse of alpha_t[ll],[lb]

    float2 pl[PF]; float pb[PF];                 // emission prefetch pipeline
    #pragma unroll
    for (int k = 0; k < PF; ++k) {
        int tp = 1 + k; if (tp > T - 1) tp = T - 1;
        pl[k] = *(const float2*)(eLb + (size_t)tp * 128 + 2 * lane);
        pb[k] = eBb[tp];
    }

    #pragma unroll PF
    for (int t = 1; t < T; ++t) {
        int ib = (t - 1) & (PF - 1);
        float ex0 = pl[ib].x, ex1 = pl[ib].y, eb = pb[ib];
        int tp = t + PF; if (tp > T - 1) tp = T - 1;
        pl[ib] = *(const float2*)(eLb + (size_t)tp * 128 + 2 * lane);
        pb[ib] = eBb[tp];

        float q = lse2(a1, a0);                  // alpha_{t-1} pair (4i+3,4i+2)
        float r = lse2(a3, a2);                  // alpha_{t-1} pair (4i+5,4i+4)
        float w = slot0 ? q : r;                 // lse(alpha_{t-1}[ll],[lb])
        float mn = fmaxf(m_es, w);
        s_es = s_es * x2(m_es - mn) + x2(w - mn);
        m_es = mn;

        float s1c = lse2(s1, 0.0f);              // lane0 combined (s1, star)
        float ur = __shfl_up(r, 1);              // lse2(u3,u2) from lane i-1
        float u3 = __shfl_up(a3, 1);             // alpha_{t-1}[4i+1]
        float uc = skipA ? ur : u3;
        if (lane == 0) uc = s1c;
        float n0 = ex0 + lse2(a0, uc);           // s = 4i+2
        float n1 = eb  + q;                      // s = 4i+3
        float n2v = ex1 + lse2(a2, skipB ? q : a1); // s = 4i+4
        float n3 = eb  + r;                      // s = 4i+5
        s1 = eb + s1c;                           // s = 1
        a0 = n0; a1 = n1; a2 = n2v; a3 = n3;
    }
    {   // final alpha_{T-1}[ll],[lb] contribution
        float q = lse2(a1, a0);
        float r = lse2(a3, a2);
        float w = slot0 ? q : r;
        float mn = fmaxf(m_es, w);
        s_es = s_es * x2(m_es - mn) + x2(w - mn);
        m_es = mn;
    }
    float mt = __shfl(m_es, lane_e);
    float st = __shfl(s_es, lane_e);
    if (lane == 0) nll[b] = -((mt + lg2(st)) * LN2);   // back to nats
}

// Phase 3: out = mean_b( nll[b] / tlen[b] )
__global__ __launch_bounds__(64) void fin_kernel(const float* __restrict__ nll,
                                                 const int* __restrict__ tlen,
                                                 float* __restrict__ out, int B) {
    int tid = threadIdx.x;
    float v = (tid < B) ? nll[tid] / (float)tlen[tid] : 0.f;
    #pragma unroll
    for (int off = 32; off > 0; off >>= 1) v += __shfl_xor(v, off);
    if (tid == 0) out[0] = v / (float)B;
}

extern "C" void kernel_launch(void* const* d_in, const int* in_sizes, int n_in,
                              void* d_out, int out_size, void* d_ws, size_t ws_size,
                              hipStream_t stream) {
    const float* pred   = (const float*)d_in[0];
    const int*   target = (const int*)d_in[1];
    const int*   tlen   = (const int*)d_in[2];
    int B = in_sizes[2];
    int L = in_sizes[1] / B;            // 128
    int V = 1000;                       // fixed by the problem
    int T = in_sizes[0] / (B * V);      // 1024

    float* ws  = (float*)d_ws;
    float* nll = ws;                    // 64 floats
    float* emb = ws + 64;               // B*T floats (blank log2-probs)
    float* em  = ws + 64 + B * T;       // B*T*128 floats (~16.8 MB), fully
                                        // rewritten by emit_kernel each launch

    emit_kernel<<<(B * T) / 4, 256, 0, stream>>>(pred, target, em, emb, T, V, L);
    dp_kernel<<<B, 64, 0, stream>>>(em, emb, target, tlen, nll, T, L);
    fin_kernel<<<1, 64, 0, stream>>>(nll, tlen, (float*)d_out, B);
}

// Round 4
// 364.919 us; speedup vs baseline: 1.4492x; 1.4121x over previous
//
#include <hip/hip_runtime.h>

#define LOG2E 1.4426950408889634f
#define LN2   0.6931471805599453f
#define NEGF  -1.0e30f

__device__ __forceinline__ float x2(float x)  { return __builtin_amdgcn_exp2f(x); }
__device__ __forceinline__ float lg2(float x) { return __builtin_amdgcn_logf(x); }

// lse2 in log2 domain: 2 transcendentals. Sentinel-safe: both NEG -> NEG+1;
// one NEG -> other exactly.
__device__ __forceinline__ float lse2(float x, float y) {
    float m = fmaxf(x, y);
    float d = -fabsf(x - y);
    return m + lg2(1.0f + x2(d));
}

// Phase 1: per-(b,t) log-softmax normalizer + gather token log2-probs.
// Labels -> em[row*128 + j]; blank -> emb[row]. One wave per row, 4 waves
// per block, no LDS, no barriers.
__global__ __launch_bounds__(256) void emit_kernel(const float* __restrict__ pred,
                                                   const int* __restrict__ target,
                                                   float* __restrict__ em,
                                                   float* __restrict__ emb,
                                                   int T, int V, int L) {
    int wave = threadIdx.x >> 6;
    int lane = threadIdx.x & 63;
    int row = blockIdx.x * 4 + wave;            // row = b*T + t
    const float* rowp = pred + (size_t)row * V;
    int nq = V >> 2;                            // 250 float4s
    float4 v0, v1, v2, v3;
    const float4 fill = make_float4(-3.0e38f, -3.0e38f, -3.0e38f, -3.0e38f);
    v0 = (lane       < nq) ? ((const float4*)rowp)[lane]       : fill;
    v1 = (lane + 64  < nq) ? ((const float4*)rowp)[lane + 64]  : fill;
    v2 = (lane + 128 < nq) ? ((const float4*)rowp)[lane + 128] : fill;
    v3 = (lane + 192 < nq) ? ((const float4*)rowp)[lane + 192] : fill;
    float lm = fmaxf(fmaxf(fmaxf(v0.x, v0.y), fmaxf(v0.z, v0.w)),
               fmaxf(fmaxf(fmaxf(v1.x, v1.y), fmaxf(v1.z, v1.w)),
               fmaxf(fmaxf(fmaxf(v2.x, v2.y), fmaxf(v2.z, v2.w)),
                     fmaxf(fmaxf(v3.x, v3.y), fmaxf(v3.z, v3.w)))));
    #pragma unroll
    for (int off = 32; off > 0; off >>= 1) lm = fmaxf(lm, __shfl_xor(lm, off));
    float mm = lm * LOG2E;                      // row max in log2 units
    float ls = 0.f;
    if (lane < nq)
        ls += x2(fmaf(v0.x, LOG2E, -mm)) + x2(fmaf(v0.y, LOG2E, -mm))
            + x2(fmaf(v0.z, LOG2E, -mm)) + x2(fmaf(v0.w, LOG2E, -mm));
    if (lane + 64 < nq)
        ls += x2(fmaf(v1.x, LOG2E, -mm)) + x2(fmaf(v1.y, LOG2E, -mm))
            + x2(fmaf(v1.z, LOG2E, -mm)) + x2(fmaf(v1.w, LOG2E, -mm));
    if (lane + 128 < nq)
        ls += x2(fmaf(v2.x, LOG2E, -mm)) + x2(fmaf(v2.y, LOG2E, -mm))
            + x2(fmaf(v2.z, LOG2E, -mm)) + x2(fmaf(v2.w, LOG2E, -mm));
    if (lane + 192 < nq)
        ls += x2(fmaf(v3.x, LOG2E, -mm)) + x2(fmaf(v3.y, LOG2E, -mm))
            + x2(fmaf(v3.z, LOG2E, -mm)) + x2(fmaf(v3.w, LOG2E, -mm));
    #pragma unroll
    for (int off = 32; off > 0; off >>= 1) ls += __shfl_xor(ls, off);
    float n2 = mm + lg2(ls);                    // log2 normalizer

    int b = row / T;
    const int* tg = target + b * L;
    float* emrow = em + (size_t)row * 128;
    for (int j = lane; j < L; j += 64) {
        int tok = tg[j];
        emrow[j] = fmaf(rowp[tok], LOG2E, -n2); // L1-hot gather (row just read)
    }
    if (lane == 0) emb[row] = fmaf(v0.x, LOG2E, -n2);  // blank = token 0
}

// One DP step consuming named prefetch registers EL (float2 labels) / EC
// (blank), then reloading them 8 steps ahead. No arrays -> no alloca -> no
// LDS promotion (R3's 770-cyc/step bug). shfls issue early so the ~10
// independent transcendentals hide bpermute latency.
#define DP_STEP(EL, EC)                                                   \
  do {                                                                    \
    float ex0 = EL.x, ex1 = EL.y, eb = EC;                                \
    int tp = t + 8; if (tp > Tm1) tp = Tm1;                               \
    EL = *(const float2*)(eLb + (size_t)tp * 128 + 2 * lane);             \
    EC = eBb[tp];                                                         \
    float r  = lse2(a3, a2);                                              \
    float ur = __shfl_up(r, 1);                                           \
    float u3 = __shfl_up(a3, 1);                                          \
    float q  = lse2(a1, a0);                                              \
    float w  = slot0 ? q : r;                                             \
    float mn = fmaxf(m_es, w);                                            \
    s_es = s_es * x2(m_es - mn) + x2(w - mn);                             \
    m_es = mn;                                                            \
    float s1c = lse2(s1, 0.0f);                                           \
    float n1  = eb  + q;                                                  \
    float n2v = ex1 + lse2(a2, skipB ? q : a1);                           \
    float n3  = eb  + r;                                                  \
    float uc  = skipA ? ur : u3;                                          \
    if (lane == 0) uc = s1c;                                              \
    a0 = ex0 + lse2(a0, uc);                                              \
    s1 = eb + s1c;                                                        \
    a1 = n1; a2 = n2v; a3 = n3;                                           \
    ++t;                                                                  \
  } while (0)

// Phase 2: barrier-free single-wave W-CTC DP, log2 domain. Lane i owns
// states s=4i+2..4i+5 in registers; star (s=0, identically 0) and s=1 are
// lane-0 side state. End-star/total streams lse of alpha_t[ll],[lb] via the
// shared q/r pair values (pre-update alpha in-loop + one post-loop step).
__global__ __launch_bounds__(64) void dp_kernel(const float* __restrict__ em,
                                                const float* __restrict__ emb,
                                                const int* __restrict__ target,
                                                const int* __restrict__ tlen,
                                                float* __restrict__ nll,
                                                int T, int L) {
    int b = blockIdx.x;
    int lane = threadIdx.x;
    const float* eLb = em + (size_t)b * T * 128;
    const float* eBb = emb + (size_t)b * T;
    const int* tg = target + b * L;
    int Tm1 = T - 1;

    int t0 = tg[2 * lane];
    int t1 = tg[2 * lane + 1];
    int tprev = __shfl_up(t1, 1);                // garbage on lane 0 (unused)
    bool skipA = (lane == 0) || (t0 != tprev);
    bool skipB = (t1 != t0);

    int tl = tlen[b];
    int ll = 2 * tl;
    int lane_e = (ll - 2) >> 2;
    bool slot0 = ((ll - 2) & 3) == 0;            // ll,lb in (a0,a1) vs (a2,a3)

    // t=0 init: s=0 -> 0 (constant star), s=1 -> blank em, s=2 -> label0 em
    float2 e0 = *(const float2*)(eLb + 2 * lane);
    float a0 = (lane == 0) ? e0.x : NEGF;
    float a1 = NEGF, a2 = NEGF, a3 = NEGF;
    float s1 = (lane == 0) ? eBb[0] : NEGF;

    float m_es = NEGF, s_es = 0.f;               // streaming lse of alpha_t[ll],[lb]

    // 8 named prefetch register sets (NOT arrays — avoids alloca->LDS)
    float2 L0, L1, L2, L3, L4, L5, L6, L7;
    float  C0, C1, C2, C3, C4, C5, C6, C7;
    #define PRELOAD(K)                                                     \
      { int tp = 1 + K; if (tp > Tm1) tp = Tm1;                            \
        L##K = *(const float2*)(eLb + (size_t)tp * 128 + 2 * lane);        \
        C##K = eBb[tp]; }
    PRELOAD(0) PRELOAD(1) PRELOAD(2) PRELOAD(3)
    PRELOAD(4) PRELOAD(5) PRELOAD(6) PRELOAD(7)
    #undef PRELOAD

    int t = 1;
    int ng = (T - 1) >> 3;                       // full groups of 8 steps
    for (int g = 0; g < ng; ++g) {
        DP_STEP(L0, C0); DP_STEP(L1, C1); DP_STEP(L2, C2); DP_STEP(L3, C3);
        DP_STEP(L4, C4); DP_STEP(L5, C5); DP_STEP(L6, C6); DP_STEP(L7, C7);
    }
    // tail (< 8 steps): registers already hold rows t..T-1 (clamped preloads)
    if (t < T) DP_STEP(L0, C0);
    if (t < T) DP_STEP(L1, C1);
    if (t < T) DP_STEP(L2, C2);
    if (t < T) DP_STEP(L3, C3);
    if (t < T) DP_STEP(L4, C4);
    if (t < T) DP_STEP(L5, C5);
    if (t < T) DP_STEP(L6, C6);

    {   // final alpha_{T-1}[ll],[lb] contribution
        float q = lse2(a1, a0);
        float r = lse2(a3, a2);
        float w = slot0 ? q : r;
        float mn = fmaxf(m_es, w);
        s_es = s_es * x2(m_es - mn) + x2(w - mn);
        m_es = mn;
    }
    float mt = __shfl(m_es, lane_e);
    float st = __shfl(s_es, lane_e);
    if (lane == 0) nll[b] = -((mt + lg2(st)) * LN2);   // back to nats
}

// Phase 3: out = mean_b( nll[b] / tlen[b] )
__global__ __launch_bounds__(64) void fin_kernel(const float* __restrict__ nll,
                                                 const int* __restrict__ tlen,
                                                 float* __restrict__ out, int B) {
    int tid = threadIdx.x;
    float v = (tid < B) ? nll[tid] / (float)tlen[tid] : 0.f;
    #pragma unroll
    for (int off = 32; off > 0; off >>= 1) v += __shfl_xor(v, off);
    if (tid == 0) out[0] = v / (float)B;
}

extern "C" void kernel_launch(void* const* d_in, const int* in_sizes, int n_in,
                              void* d_out, int out_size, void* d_ws, size_t ws_size,
                              hipStream_t stream) {
    const float* pred   = (const float*)d_in[0];
    const int*   target = (const int*)d_in[1];
    const int*   tlen   = (const int*)d_in[2];
    int B = in_sizes[2];
    int L = in_sizes[1] / B;            // 128
    int V = 1000;                       // fixed by the problem
    int T = in_sizes[0] / (B * V);      // 1024

    float* ws  = (float*)d_ws;
    float* nll = ws;                    // 64 floats
    float* emb = ws + 64;               // B*T floats (blank log2-probs)
    float* em  = ws + 64 + B * T;       // B*T*128 floats (~16.8 MB), fully
                                        // rewritten by emit_kernel each launch

    emit_kernel<<<(B * T) / 4, 256, 0, stream>>>(pred, target, em, emb, T, V, L);
    dp_kernel<<<B, 64, 0, stream>>>(em, emb, target, tlen, nll, T, L);
    fin_kernel<<<1, 64, 0, stream>>>(nll, tlen, (float*)d_out, B);
}

// Round 5
// 334.749 us; speedup vs baseline: 1.5799x; 1.0901x over previous
//
#include <hip/hip_runtime.h>

#define LOG2E 1.4426950408889634f
#define LN2   0.6931471805599453f

__device__ __forceinline__ float x2(float x)  { return __builtin_amdgcn_exp2f(x); }
__device__ __forceinline__ float lg2(float x) { return __builtin_amdgcn_logf(x); }

// Phase 1: per-(b,t) softmax normalizer + gather token PROBABILITIES (linear
// domain: p = 2^(log2 softmax)). Labels -> em[row*128 + j]; blank -> emb[row].
// One wave per row, 4 waves per block, no LDS, no barriers.
__global__ __launch_bounds__(256) void emit_kernel(const float* __restrict__ pred,
                                                   const int* __restrict__ target,
                                                   float* __restrict__ em,
                                                   float* __restrict__ emb,
                                                   int T, int V, int L) {
    int wave = threadIdx.x >> 6;
    int lane = threadIdx.x & 63;
    int row = blockIdx.x * 4 + wave;            // row = b*T + t
    const float* rowp = pred + (size_t)row * V;
    int nq = V >> 2;                            // 250 float4s
    float4 v0, v1, v2, v3;
    const float4 fill = make_float4(-3.0e38f, -3.0e38f, -3.0e38f, -3.0e38f);
    v0 = (lane       < nq) ? ((const float4*)rowp)[lane]       : fill;
    v1 = (lane + 64  < nq) ? ((const float4*)rowp)[lane + 64]  : fill;
    v2 = (lane + 128 < nq) ? ((const float4*)rowp)[lane + 128] : fill;
    v3 = (lane + 192 < nq) ? ((const float4*)rowp)[lane + 192] : fill;
    float lm = fmaxf(fmaxf(fmaxf(v0.x, v0.y), fmaxf(v0.z, v0.w)),
               fmaxf(fmaxf(fmaxf(v1.x, v1.y), fmaxf(v1.z, v1.w)),
               fmaxf(fmaxf(fmaxf(v2.x, v2.y), fmaxf(v2.z, v2.w)),
                     fmaxf(fmaxf(v3.x, v3.y), fmaxf(v3.z, v3.w)))));
    #pragma unroll
    for (int off = 32; off > 0; off >>= 1) lm = fmaxf(lm, __shfl_xor(lm, off));
    float mm = lm * LOG2E;                      // row max in log2 units
    float ls = 0.f;
    if (lane < nq)
        ls += x2(fmaf(v0.x, LOG2E, -mm)) + x2(fmaf(v0.y, LOG2E, -mm))
            + x2(fmaf(v0.z, LOG2E, -mm)) + x2(fmaf(v0.w, LOG2E, -mm));
    if (lane + 64 < nq)
        ls += x2(fmaf(v1.x, LOG2E, -mm)) + x2(fmaf(v1.y, LOG2E, -mm))
            + x2(fmaf(v1.z, LOG2E, -mm)) + x2(fmaf(v1.w, LOG2E, -mm));
    if (lane + 128 < nq)
        ls += x2(fmaf(v2.x, LOG2E, -mm)) + x2(fmaf(v2.y, LOG2E, -mm))
            + x2(fmaf(v2.z, LOG2E, -mm)) + x2(fmaf(v2.w, LOG2E, -mm));
    if (lane + 192 < nq)
        ls += x2(fmaf(v3.x, LOG2E, -mm)) + x2(fmaf(v3.y, LOG2E, -mm))
            + x2(fmaf(v3.z, LOG2E, -mm)) + x2(fmaf(v3.w, LOG2E, -mm));
    #pragma unroll
    for (int off = 32; off > 0; off >>= 1) ls += __shfl_xor(ls, off);
    float n2 = mm + lg2(ls);                    // log2 normalizer

    int b = row / T;
    const int* tg = target + b * L;
    float* emrow = em + (size_t)row * 128;
    for (int j = lane; j < L; j += 64) {
        int tok = tg[j];
        emrow[j] = x2(fmaf(rowp[tok], LOG2E, -n2));   // linear probability
    }
    if (lane == 0) emb[row] = x2(fmaf(v0.x, LOG2E, -n2));  // blank = token 0
}

// One linear-domain DP step. Named prefetch regs (no arrays -> no LDS
// promotion). stored = true * 2^K per lane; neighbor values re-framed by
// ldexp(dK). Inactive lanes adopt neighbor K each step so arriving mass
// lands at the correct scale. Zero transcendentals in-loop.
#define DP_STEP(EL, EC)                                                   \
  do {                                                                    \
    float ex0 = EL.x, ex1 = EL.y, eb = EC;                                \
    int tp = t + 8; if (tp > Tm1) tp = Tm1;                               \
    EL = *(const float2*)(eLb + (size_t)tp * 128 + 2 * lane);             \
    EC = eBb[tp];                                                         \
    float r  = a3 + a2;                                                   \
    float q  = a1 + a0;                                                   \
    int   Kp = __shfl_up(K, 1);                                           \
    float u3 = __shfl_up(a3, 1);                                          \
    float ur = __shfl_up(r, 1);                                           \
    K = act ? K : Kp;                                                     \
    float uc = skipA ? ur : u3;                                           \
    uc = ldexpf(uc, K - Kp);                                              \
    float sb = s1 + star_st;                                              \
    if (lane == 0) uc = sb;                                               \
    S += slot0 ? q : r;                                                   \
    float n2v = ex1 * (a2 + (skipB ? q : a1));                            \
    a0 = ex0 * (a0 + uc);                                                 \
    a1 = eb * q;                                                          \
    a2 = n2v;                                                             \
    a3 = eb * r;                                                          \
    s1 = eb * sb;                                                         \
    act = act || (uc > 0.0f);                                             \
    ++t;                                                                  \
  } while (0)

// Per-lane renorm: rescale stored values so lane max ~ 1, fold into K.
// Inactive lanes (m4==0) keep K (adoption handles them). S shares the frame.
#define RENORM                                                            \
  do {                                                                    \
    float m4 = fmaxf(fmaxf(a0, a1), fmaxf(a2, a3));                       \
    int e = (int)((__float_as_uint(m4) >> 23) & 255u) - 127;              \
    int d = act ? -e : 0;                                                 \
    float sc = ldexpf(1.0f, d);                                           \
    a0 *= sc; a1 *= sc; a2 *= sc; a3 *= sc; s1 *= sc; S *= sc;            \
    K += d;                                                               \
    star_st = ldexpf(sbase, K);                                           \
  } while (0)

// Phase 2: barrier-free single-wave W-CTC DP, LINEAR domain with per-lane
// block exponents. Lane i owns states s=4i+2..4i+5; star (true value 1) and
// s=1 live on lane 0. total = sum over t of (alpha_t[ll] + alpha_t[lb]).
__global__ __launch_bounds__(64) void dp_kernel(const float* __restrict__ em,
                                                const float* __restrict__ emb,
                                                const int* __restrict__ target,
                                                const int* __restrict__ tlen,
                                                float* __restrict__ nll,
                                                int T, int L) {
    int b = blockIdx.x;
    int lane = threadIdx.x;
    const float* eLb = em + (size_t)b * T * 128;
    const float* eBb = emb + (size_t)b * T;
    const int* tg = target + b * L;
    int Tm1 = T - 1;

    int t0 = tg[2 * lane];
    int t1 = tg[2 * lane + 1];
    int tprev = __shfl_up(t1, 1);                // garbage on lane 0 (unused)
    bool skipA = (lane == 0) || (t0 != tprev);
    bool skipB = (t1 != t0);

    int tl = tlen[b];
    int ll = 2 * tl;
    int lane_e = (ll - 2) >> 2;
    bool slot0 = ((ll - 2) & 3) == 0;            // ll,lb in (a0,a1) vs (a2,a3)

    // t=0 init (linear): star=1 (lane0), s=1 -> blank prob, s=2 -> label0 prob
    float2 e0 = *(const float2*)(eLb + 2 * lane);
    float a0 = (lane == 0) ? e0.x : 0.f;
    float a1 = 0.f, a2 = 0.f, a3 = 0.f;
    float s1 = (lane == 0) ? eBb[0] : 0.f;
    float sbase = (lane == 0) ? 1.0f : 0.0f;
    int   K = 0;
    float star_st = sbase;                       // star stored = 1 * 2^K (lane 0)
    bool  act = (lane == 0);
    float S = 0.f;                               // running sum of alpha_t[ll]+[lb]

    // 8 named prefetch register sets (NOT arrays — avoids alloca->LDS)
    float2 L0, L1, L2, L3, L4, L5, L6, L7;
    float  C0, C1, C2, C3, C4, C5, C6, C7;
    #define PRELOAD(KK)                                                    \
      { int tp = 1 + KK; if (tp > Tm1) tp = Tm1;                           \
        L##KK = *(const float2*)(eLb + (size_t)tp * 128 + 2 * lane);       \
        C##KK = eBb[tp]; }
    PRELOAD(0) PRELOAD(1) PRELOAD(2) PRELOAD(3)
    PRELOAD(4) PRELOAD(5) PRELOAD(6) PRELOAD(7)
    #undef PRELOAD

    int t = 1;
    int ng = (T - 1) >> 3;                       // full groups of 8 steps
    for (int g = 0; g < ng; ++g) {
        DP_STEP(L0, C0); DP_STEP(L1, C1); DP_STEP(L2, C2); DP_STEP(L3, C3);
        RENORM;
        DP_STEP(L4, C4); DP_STEP(L5, C5); DP_STEP(L6, C6); DP_STEP(L7, C7);
        RENORM;
    }
    // tail (< 8 steps): registers already hold rows t..T-1 (clamped preloads)
    if (t < T) DP_STEP(L0, C0);
    if (t < T) DP_STEP(L1, C1);
    if (t < T) DP_STEP(L2, C2);
    if (t < T) DP_STEP(L3, C3);
    if (t < T) DP_STEP(L4, C4);
    if (t < T) DP_STEP(L5, C5);
    if (t < T) DP_STEP(L6, C6);

    {   // final alpha_{T-1}[ll],[lb] contribution
        float q = a1 + a0;
        float r = a3 + a2;
        S += slot0 ? q : r;
    }
    float Sv = __shfl(S, lane_e);
    int   Kv = __shfl(K, lane_e);
    if (lane == 0) nll[b] = -((lg2(Sv) - (float)Kv) * LN2);   // back to nats
}

// Phase 3: out = mean_b( nll[b] / tlen[b] )
__global__ __launch_bounds__(64) void fin_kernel(const float* __restrict__ nll,
                                                 const int* __restrict__ tlen,
                                                 float* __restrict__ out, int B) {
    int tid = threadIdx.x;
    float v = (tid < B) ? nll[tid] / (float)tlen[tid] : 0.f;
    #pragma unroll
    for (int off = 32; off > 0; off >>= 1) v += __shfl_xor(v, off);
    if (tid == 0) out[0] = v / (float)B;
}

extern "C" void kernel_launch(void* const* d_in, const int* in_sizes, int n_in,
                              void* d_out, int out_size, void* d_ws, size_t ws_size,
                              hipStream_t stream) {
    const float* pred   = (const float*)d_in[0];
    const int*   target = (const int*)d_in[1];
    const int*   tlen   = (const int*)d_in[2];
    int B = in_sizes[2];
    int L = in_sizes[1] / B;            // 128
    int V = 1000;                       // fixed by the problem
    int T = in_sizes[0] / (B * V);      // 1024

    float* ws  = (float*)d_ws;
    float* nll = ws;                    // 64 floats
    float* emb = ws + 64;               // B*T floats (blank probs)
    float* em  = ws + 64 + B * T;       // B*T*128 floats (~16.8 MB), fully
                                        // rewritten by emit_kernel each launch

    emit_kernel<<<(B * T) / 4, 256, 0, stream>>>(pred, target, em, emb, T, V, L);
    dp_kernel<<<B, 64, 0, stream>>>(em, emb, target, tlen, nll, T, L);
    fin_kernel<<<1, 64, 0, stream>>>(nll, tlen, (float*)d_out, B);
}